// Round 5
// baseline (425.354 us; speedup 1.0000x reference)
//
#include <hip/hip_runtime.h>

#define NN 50000
#define CAP 32          // per-node bin capacity; overflow handled correctly
#define OVF_CAP 4096

// Sharded bin fill (R4) + non-temporal edge reads (R5): the streaming edge
// list reads were evicting dirty bin lines from L2 mid-scan (R4: WRITE 68MB
// vs 12.8MB footprint). NT loads keep the bin lines resident so the ~16
// 4B stores per 128B line merge before writeback.
__global__ __launch_bounds__(256) void bin_fill(
    const int* __restrict__ ei0, int E0,
    const int* __restrict__ ei1, int E1,
    int* __restrict__ deg,       // [2*NN]
    int* __restrict__ bins,      // [2*NN][CAP]
    int2* __restrict__ ovf, int* __restrict__ ovf_cnt)
{
    int shard = blockIdx.x & 7;
    int lblk  = blockIdx.x >> 3;
    int lgrid = gridDim.x >> 3;
    int total = E0 + E1;
    int stride = lgrid * blockDim.x;
    for (int t = lblk * blockDim.x + threadIdx.x; t < total; t += stride) {
        int node;
        const int* srcp;
        if (t < E0) { node = __builtin_nontemporal_load(ei0 + E0 + t); srcp = ei0 + t; }
        else        { int u = t - E0;
                      node = NN + __builtin_nontemporal_load(ei1 + E1 + u); srcp = ei1 + u; }
        if ((node & 7) == shard) {
            int s = __builtin_nontemporal_load(srcp);
            int r = atomicAdd(&deg[node], 1);
            if (r < CAP) {
                bins[(size_t)node * CAP + r] = s;
            } else {
                int o = atomicAdd(ovf_cnt, 1);
                if (o < OVF_CAP) ovf[o] = make_int2(node, s);
            }
        }
    }
}

// One wave per node, BOTH relations concurrently: 8 independent gather chains
// (R4's 4-chain version was latency-bound at ~70us; BW arithmetic says ~25us).
// Guards (t+u < m) are wave-uniform scalar branches.
__global__ __launch_bounds__(256) void aggregate(
    const int* __restrict__ bins, const int* __restrict__ deg,
    const float* __restrict__ h, float* __restrict__ agg)
{
    int lane = threadIdx.x & 63;
    int wid = (blockIdx.x * blockDim.x + threadIdx.x) >> 6;
    int nwaves = (gridDim.x * blockDim.x) >> 6;
    for (int i = wid; i < NN; i += nwaves) {
        int tA = i, tB = NN + i;
        int dA = deg[tA], dB = deg[tB];
        int mA = min(dA, CAP), mB = min(dB, CAP);
        int idxA = 0, idxB = 0;
        if (lane < mA) idxA = bins[(size_t)tA * CAP + lane];
        if (lane < mB) idxB = bins[(size_t)tB * CAP + lane];
        float a0=0.f,a1=0.f,a2=0.f,a3=0.f;
        float b0=0.f,b1=0.f,b2=0.f,b3=0.f;
        int mmax = max(mA, mB);
        for (int t = 0; t < mmax; t += 4) {
            int sA0=__shfl(idxA,t+0), sA1=__shfl(idxA,t+1);
            int sA2=__shfl(idxA,t+2), sA3=__shfl(idxA,t+3);
            int sB0=__shfl(idxB,t+0), sB1=__shfl(idxB,t+1);
            int sB2=__shfl(idxB,t+2), sB3=__shfl(idxB,t+3);
            if (t+0 < mA) a0 += h[(size_t)sA0 * 64 + lane];
            if (t+0 < mB) b0 += h[(size_t)sB0 * 64 + lane];
            if (t+1 < mA) a1 += h[(size_t)sA1 * 64 + lane];
            if (t+1 < mB) b1 += h[(size_t)sB1 * 64 + lane];
            if (t+2 < mA) a2 += h[(size_t)sA2 * 64 + lane];
            if (t+2 < mB) b2 += h[(size_t)sB2 * 64 + lane];
            if (t+3 < mA) a3 += h[(size_t)sA3 * 64 + lane];
            if (t+3 < mB) b3 += h[(size_t)sB3 * 64 + lane];
        }
        agg[(size_t)tA * 64 + lane] = ((a0+a1)+(a2+a3)) / (float)max(dA, 1);
        agg[(size_t)tB * 64 + lane] = ((b0+b1)+(b2+b3)) / (float)max(dB, 1);
    }
}

// Add overflowed edges' contribution (already-divided) into agg. Usually 0 work.
__global__ __launch_bounds__(256) void ovf_fix(
    const int2* __restrict__ ovf, const int* __restrict__ ovf_cnt,
    const int* __restrict__ deg, const float* __restrict__ h,
    float* __restrict__ agg)
{
    int cnt = min(*ovf_cnt, OVF_CAP);
    int total = cnt * 64;
    int stride = gridDim.x * blockDim.x;
    for (int t = blockIdx.x * blockDim.x + threadIdx.x; t < total; t += stride) {
        int e = t >> 6, f = t & 63;
        int2 v = ovf[e];
        float val = h[(size_t)v.y * 64 + f] / (float)max(deg[v.x], 1);
        atomicAdd(&agg[(size_t)v.x * 64 + f], val);
    }
}

// hout = relu(mean0@Wl0 + mean1@Wl1 + h@(Wr0+Wr1) + (b0+b1))
// Register-tiled: block = 128 nodes x 64 cols, thread = 4 nodes x 8 cols.
// K in 3 chunks of 64. Features staged transposed -> 1.5 B LDS/FMA.
#define RST 132   // rowsT row stride: 128 nodes + pad, %4==0 for b128 reads
__global__ __launch_bounds__(256) void layer_gemm(
    const float* __restrict__ agg0, const float* __restrict__ agg1,
    const float* __restrict__ h,
    const float* __restrict__ Wl0, const float* __restrict__ Wl1,
    const float* __restrict__ Wr0, const float* __restrict__ Wr1,
    const float* __restrict__ b0, const float* __restrict__ b1,
    float* __restrict__ hout)
{
    __shared__ float Wch[64 * 64];
    __shared__ float rowsT[64 * RST];
    __shared__ float bias[64];

    int tid = threadIdx.x;
    int base = blockIdx.x * 128;
    if (tid < 64) bias[tid] = b0[tid] + b1[tid];

    int j8 = (tid & 7) * 8;
    int n4 = (tid >> 3) * 4;

    float acc[4][8];
    #pragma unroll
    for (int i = 0; i < 4; i++)
        #pragma unroll
        for (int c = 0; c < 8; c++) acc[i][c] = 0.f;

    for (int chunk = 0; chunk < 3; chunk++) {
        const float* W   = (chunk == 0) ? Wl0  : (chunk == 1) ? Wl1  : Wr0;
        const float* src = (chunk == 0) ? agg0 : (chunk == 1) ? agg1 : h;
        __syncthreads();
        #pragma unroll
        for (int r = 0; r < 4; r++) {
            int i = tid + 256 * r;
            float4 w = *(const float4*)&W[i * 4];
            if (chunk == 2) {
                float4 w2 = *(const float4*)&Wr1[i * 4];
                w.x += w2.x; w.y += w2.y; w.z += w2.z; w.w += w2.w;
            }
            *(float4*)&Wch[i * 4] = w;
        }
        #pragma unroll
        for (int r = 0; r < 8; r++) {
            int i = tid + 256 * r;
            int node = i >> 4;
            int k4 = (i & 15) * 4;
            float4 v = make_float4(0.f, 0.f, 0.f, 0.f);
            int g = base + node;
            if (g < NN) v = *(const float4*)&src[(size_t)g * 64 + k4];
            rowsT[(k4 + 0) * RST + node] = v.x;
            rowsT[(k4 + 1) * RST + node] = v.y;
            rowsT[(k4 + 2) * RST + node] = v.z;
            rowsT[(k4 + 3) * RST + node] = v.w;
        }
        __syncthreads();
        #pragma unroll 4
        for (int k = 0; k < 64; k++) {
            float4 wa = *(const float4*)&Wch[k * 64 + j8];
            float4 wb = *(const float4*)&Wch[k * 64 + j8 + 4];
            float4 rv = *(const float4*)&rowsT[k * RST + n4];
            float w[8] = {wa.x, wa.y, wa.z, wa.w, wb.x, wb.y, wb.z, wb.w};
            float rr[4] = {rv.x, rv.y, rv.z, rv.w};
            #pragma unroll
            for (int i = 0; i < 4; i++)
                #pragma unroll
                for (int c = 0; c < 8; c++)
                    acc[i][c] = fmaf(rr[i], w[c], acc[i][c]);
        }
    }

    #pragma unroll
    for (int i = 0; i < 4; i++) {
        int g = base + n4 + i;
        if (g < NN) {
            float4 o1, o2;
            o1.x = fmaxf(acc[i][0] + bias[j8 + 0], 0.f);
            o1.y = fmaxf(acc[i][1] + bias[j8 + 1], 0.f);
            o1.z = fmaxf(acc[i][2] + bias[j8 + 2], 0.f);
            o1.w = fmaxf(acc[i][3] + bias[j8 + 3], 0.f);
            o2.x = fmaxf(acc[i][4] + bias[j8 + 4], 0.f);
            o2.y = fmaxf(acc[i][5] + bias[j8 + 5], 0.f);
            o2.z = fmaxf(acc[i][6] + bias[j8 + 6], 0.f);
            o2.w = fmaxf(acc[i][7] + bias[j8 + 7], 0.f);
            *(float4*)&hout[(size_t)g * 64 + j8]     = o1;
            *(float4*)&hout[(size_t)g * 64 + j8 + 4] = o2;
        }
    }
}

// out[i,:32] = h[i,:64] @ W + b
__global__ __launch_bounds__(256) void final_gemm(
    const float* __restrict__ h, const float* __restrict__ W,
    const float* __restrict__ b, float* __restrict__ out)
{
    __shared__ float Ws[64 * 32];
    __shared__ float bs[32];
    __shared__ float rows[8][64];

    int tid = threadIdx.x;
    for (int i = tid; i < 2048; i += 256) Ws[i] = W[i];
    if (tid < 32) bs[tid] = b[tid];

    int j = tid & 31;
    int nl = tid >> 5;

    for (int base = blockIdx.x * 8; base < NN; base += gridDim.x * 8) {
        __syncthreads();
        if (tid < 128) {
            int n = tid >> 4, kq = tid & 15;
            int node = base + n;
            float4 v = make_float4(0.f, 0.f, 0.f, 0.f);
            if (node < NN) v = *(const float4*)&h[(size_t)node * 64 + kq * 4];
            *(float4*)&rows[n][kq * 4] = v;
        }
        __syncthreads();

        int node = base + nl;
        if (node < NN) {
            float acc = bs[j];
            #pragma unroll
            for (int k = 0; k < 64; k += 4) {
                float4 rv = *(const float4*)&rows[nl][k];
                acc = fmaf(rv.x, Ws[(k + 0) * 32 + j], acc);
                acc = fmaf(rv.y, Ws[(k + 1) * 32 + j], acc);
                acc = fmaf(rv.z, Ws[(k + 2) * 32 + j], acc);
                acc = fmaf(rv.w, Ws[(k + 3) * 32 + j], acc);
            }
            out[(size_t)node * 32 + j] = acc;
        }
    }
}

extern "C" void kernel_launch(void* const* d_in, const int* in_sizes, int n_in,
                              void* d_out, int out_size, void* d_ws, size_t ws_size,
                              hipStream_t stream)
{
    const float* x    = (const float*)d_in[0];
    const int*   ei0  = (const int*)d_in[1];
    const int*   ei1  = (const int*)d_in[2];
    const float* Wl   = (const float*)d_in[3];   // [2,2,64,64]
    const float* Wr   = (const float*)d_in[4];   // [2,2,64,64]
    const float* bl   = (const float*)d_in[5];   // [2,2,64]
    const float* linW = (const float*)d_in[6];   // [64,32]
    const float* linb = (const float*)d_in[7];   // [32]
    float* out = (float*)d_out;

    int E0 = in_sizes[1] / 2;
    int E1 = in_sizes[2] / 2;

    int*  deg     = (int*)d_ws;
    int*  ovf_cnt = deg + 2 * NN;
    int2* ovf     = (int2*)(ovf_cnt + 4);
    int*  bins    = (int*)(ovf + OVF_CAP);
    float* agg    = (float*)(bins + (size_t)2 * NN * CAP);
    float* agg0   = agg;
    float* agg1   = agg + (size_t)NN * 64;
    float* h1     = agg + (size_t)2 * NN * 64;

    dim3 blk(256);
    int ggrid = (NN + 127) / 128;   // 391

    (void)hipMemsetAsync(deg, 0, (2 * NN + 4) * sizeof(int), stream);
    bin_fill<<<2048, blk, 0, stream>>>(ei0, E0, ei1, E1, deg, bins, ovf, ovf_cnt);

    // ---- Layer 0 (input x) ----
    aggregate<<<4096, blk, 0, stream>>>(bins, deg, x, agg);
    ovf_fix<<<64, blk, 0, stream>>>(ovf, ovf_cnt, deg, x, agg);
    layer_gemm<<<ggrid, blk, 0, stream>>>(agg0, agg1, x,
        Wl + 0, Wl + 4096, Wr + 0, Wr + 4096, bl + 0, bl + 64, h1);

    // ---- Layer 1 (input h1, output in-place h1) ----
    aggregate<<<4096, blk, 0, stream>>>(bins, deg, h1, agg);
    ovf_fix<<<64, blk, 0, stream>>>(ovf, ovf_cnt, deg, h1, agg);
    layer_gemm<<<ggrid, blk, 0, stream>>>(agg0, agg1, h1,
        Wl + 8192, Wl + 12288, Wr + 8192, Wr + 12288, bl + 128, bl + 192, h1);

    // ---- Final projection ----
    final_gemm<<<768, blk, 0, stream>>>(h1, linW, linb, out);
}

// Round 6
// 327.372 us; speedup vs baseline: 1.2993x; 1.2993x over previous
//
#include <hip/hip_runtime.h>

#define NN 50000
#define CAP 32          // per-node bin capacity; overflow handled correctly
#define OVF_CAP 4096

__device__ __forceinline__ unsigned short f2bf(float f) {
    unsigned u = __float_as_uint(f);
    u += 0x7fffu + ((u >> 16) & 1u);           // round-to-nearest-even
    return (unsigned short)(u >> 16);
}
__device__ __forceinline__ float bf2f(unsigned short u) {
    return __uint_as_float(((unsigned)u) << 16);
}

// fp32 -> bf16 row copy (n4 = count of float4s)
__global__ __launch_bounds__(256) void to_bf16(
    const float* __restrict__ in, unsigned short* __restrict__ out, int n4)
{
    int stride = gridDim.x * blockDim.x;
    for (int i = blockIdx.x * blockDim.x + threadIdx.x; i < n4; i += stride) {
        float4 v = ((const float4*)in)[i];
        ushort4 o;
        o.x = f2bf(v.x); o.y = f2bf(v.y); o.z = f2bf(v.z); o.w = f2bf(v.w);
        ((ushort4*)out)[i] = o;
    }
}

// Sharded bin fill + NT edge reads (kept from R5; bin_fill left top-5 in R5).
__global__ __launch_bounds__(256) void bin_fill(
    const int* __restrict__ ei0, int E0,
    const int* __restrict__ ei1, int E1,
    int* __restrict__ deg, int* __restrict__ bins,
    int2* __restrict__ ovf, int* __restrict__ ovf_cnt)
{
    int shard = blockIdx.x & 7;
    int lblk  = blockIdx.x >> 3;
    int lgrid = gridDim.x >> 3;
    int total = E0 + E1;
    int stride = lgrid * blockDim.x;
    for (int t = lblk * blockDim.x + threadIdx.x; t < total; t += stride) {
        int node;
        const int* srcp;
        if (t < E0) { node = __builtin_nontemporal_load(ei0 + E0 + t); srcp = ei0 + t; }
        else        { int u = t - E0;
                      node = NN + __builtin_nontemporal_load(ei1 + E1 + u); srcp = ei1 + u; }
        if ((node & 7) == shard) {
            int s = __builtin_nontemporal_load(srcp);
            int r = atomicAdd(&deg[node], 1);
            if (r < CAP) {
                bins[(size_t)node * CAP + r] = s;
            } else {
                int o = atomicAdd(ovf_cnt, 1);
                if (o < OVF_CAP) ovf[o] = make_int2(node, s);
            }
        }
    }
}

// R4 structure (4 chains, one (rel,node) task per wave — measured 3.0 TB/s TCC
// throughput vs R5 variant's 2.1), gathering from BF16 h (halves footprint:
// 12.8->6.4MB so per-XCD L2 hit rate ~doubles; halves logical bytes too).
__global__ __launch_bounds__(256) void aggregate(
    const int* __restrict__ bins, const int* __restrict__ deg,
    const unsigned short* __restrict__ hb, float* __restrict__ agg)
{
    int lane = threadIdx.x & 63;
    int wid = (blockIdx.x * blockDim.x + threadIdx.x) >> 6;
    int nwaves = (gridDim.x * blockDim.x) >> 6;
    for (int task = wid; task < 2 * NN; task += nwaves) {
        int d = deg[task];
        int m = min(d, CAP);
        int idx = 0;
        if (lane < m) idx = bins[(size_t)task * CAP + lane];
        float a0 = 0.f, a1 = 0.f, a2 = 0.f, a3 = 0.f;
        int t = 0;
        for (; t + 4 <= m; t += 4) {
            int s0 = __shfl(idx, t + 0);
            int s1 = __shfl(idx, t + 1);
            int s2 = __shfl(idx, t + 2);
            int s3 = __shfl(idx, t + 3);
            a0 += bf2f(hb[(size_t)s0 * 64 + lane]);
            a1 += bf2f(hb[(size_t)s1 * 64 + lane]);
            a2 += bf2f(hb[(size_t)s2 * 64 + lane]);
            a3 += bf2f(hb[(size_t)s3 * 64 + lane]);
        }
        for (; t < m; ++t) {
            int s = __shfl(idx, t);
            a0 += bf2f(hb[(size_t)s * 64 + lane]);
        }
        float sum = (a0 + a1) + (a2 + a3);
        agg[(size_t)task * 64 + lane] = sum / (float)max(d, 1);
    }
}

// Overflow fixup stays on fp32 h (tiny work, keeps extra precision).
__global__ __launch_bounds__(256) void ovf_fix(
    const int2* __restrict__ ovf, const int* __restrict__ ovf_cnt,
    const int* __restrict__ deg, const float* __restrict__ h,
    float* __restrict__ agg)
{
    int cnt = min(*ovf_cnt, OVF_CAP);
    int total = cnt * 64;
    int stride = gridDim.x * blockDim.x;
    for (int t = blockIdx.x * blockDim.x + threadIdx.x; t < total; t += stride) {
        int e = t >> 6, f = t & 63;
        int2 v = ovf[e];
        float val = h[(size_t)v.y * 64 + f] / (float)max(deg[v.x], 1);
        atomicAdd(&agg[(size_t)v.x * 64 + f], val);
    }
}

// hout = relu(mean0@Wl0 + mean1@Wl1 + h@(Wr0+Wr1) + (b0+b1))
// Register-tiled (R4). Optional bf16 mirror of the output for the next
// layer's aggregate gather.
#define RST 132
__global__ __launch_bounds__(256) void layer_gemm(
    const float* __restrict__ agg0, const float* __restrict__ agg1,
    const float* __restrict__ h,
    const float* __restrict__ Wl0, const float* __restrict__ Wl1,
    const float* __restrict__ Wr0, const float* __restrict__ Wr1,
    const float* __restrict__ b0, const float* __restrict__ b1,
    float* __restrict__ hout, unsigned short* __restrict__ hb16)
{
    __shared__ float Wch[64 * 64];
    __shared__ float rowsT[64 * RST];
    __shared__ float bias[64];

    int tid = threadIdx.x;
    int base = blockIdx.x * 128;
    if (tid < 64) bias[tid] = b0[tid] + b1[tid];

    int j8 = (tid & 7) * 8;
    int n4 = (tid >> 3) * 4;

    float acc[4][8];
    #pragma unroll
    for (int i = 0; i < 4; i++)
        #pragma unroll
        for (int c = 0; c < 8; c++) acc[i][c] = 0.f;

    for (int chunk = 0; chunk < 3; chunk++) {
        const float* W   = (chunk == 0) ? Wl0  : (chunk == 1) ? Wl1  : Wr0;
        const float* src = (chunk == 0) ? agg0 : (chunk == 1) ? agg1 : h;
        __syncthreads();
        #pragma unroll
        for (int r = 0; r < 4; r++) {
            int i = tid + 256 * r;
            float4 w = *(const float4*)&W[i * 4];
            if (chunk == 2) {
                float4 w2 = *(const float4*)&Wr1[i * 4];
                w.x += w2.x; w.y += w2.y; w.z += w2.z; w.w += w2.w;
            }
            *(float4*)&Wch[i * 4] = w;
        }
        #pragma unroll
        for (int r = 0; r < 8; r++) {
            int i = tid + 256 * r;
            int node = i >> 4;
            int k4 = (i & 15) * 4;
            float4 v = make_float4(0.f, 0.f, 0.f, 0.f);
            int g = base + node;
            if (g < NN) v = *(const float4*)&src[(size_t)g * 64 + k4];
            rowsT[(k4 + 0) * RST + node] = v.x;
            rowsT[(k4 + 1) * RST + node] = v.y;
            rowsT[(k4 + 2) * RST + node] = v.z;
            rowsT[(k4 + 3) * RST + node] = v.w;
        }
        __syncthreads();
        #pragma unroll 4
        for (int k = 0; k < 64; k++) {
            float4 wa = *(const float4*)&Wch[k * 64 + j8];
            float4 wb = *(const float4*)&Wch[k * 64 + j8 + 4];
            float4 rv = *(const float4*)&rowsT[k * RST + n4];
            float w[8] = {wa.x, wa.y, wa.z, wa.w, wb.x, wb.y, wb.z, wb.w};
            float rr[4] = {rv.x, rv.y, rv.z, rv.w};
            #pragma unroll
            for (int i = 0; i < 4; i++)
                #pragma unroll
                for (int c = 0; c < 8; c++)
                    acc[i][c] = fmaf(rr[i], w[c], acc[i][c]);
        }
    }

    #pragma unroll
    for (int i = 0; i < 4; i++) {
        int g = base + n4 + i;
        if (g < NN) {
            float4 o1, o2;
            o1.x = fmaxf(acc[i][0] + bias[j8 + 0], 0.f);
            o1.y = fmaxf(acc[i][1] + bias[j8 + 1], 0.f);
            o1.z = fmaxf(acc[i][2] + bias[j8 + 2], 0.f);
            o1.w = fmaxf(acc[i][3] + bias[j8 + 3], 0.f);
            o2.x = fmaxf(acc[i][4] + bias[j8 + 4], 0.f);
            o2.y = fmaxf(acc[i][5] + bias[j8 + 5], 0.f);
            o2.z = fmaxf(acc[i][6] + bias[j8 + 6], 0.f);
            o2.w = fmaxf(acc[i][7] + bias[j8 + 7], 0.f);
            *(float4*)&hout[(size_t)g * 64 + j8]     = o1;
            *(float4*)&hout[(size_t)g * 64 + j8 + 4] = o2;
            if (hb16) {
                ushort4 p0, p1;
                p0.x = f2bf(o1.x); p0.y = f2bf(o1.y); p0.z = f2bf(o1.z); p0.w = f2bf(o1.w);
                p1.x = f2bf(o2.x); p1.y = f2bf(o2.y); p1.z = f2bf(o2.z); p1.w = f2bf(o2.w);
                *(ushort4*)&hb16[(size_t)g * 64 + j8]     = p0;
                *(ushort4*)&hb16[(size_t)g * 64 + j8 + 4] = p1;
            }
        }
    }
}

// out[i,:32] = h[i,:64] @ W + b   (fp32 h)
__global__ __launch_bounds__(256) void final_gemm(
    const float* __restrict__ h, const float* __restrict__ W,
    const float* __restrict__ b, float* __restrict__ out)
{
    __shared__ float Ws[64 * 32];
    __shared__ float bs[32];
    __shared__ float rows[8][64];

    int tid = threadIdx.x;
    for (int i = tid; i < 2048; i += 256) Ws[i] = W[i];
    if (tid < 32) bs[tid] = b[tid];

    int j = tid & 31;
    int nl = tid >> 5;

    for (int base = blockIdx.x * 8; base < NN; base += gridDim.x * 8) {
        __syncthreads();
        if (tid < 128) {
            int n = tid >> 4, kq = tid & 15;
            int node = base + n;
            float4 v = make_float4(0.f, 0.f, 0.f, 0.f);
            if (node < NN) v = *(const float4*)&h[(size_t)node * 64 + kq * 4];
            *(float4*)&rows[n][kq * 4] = v;
        }
        __syncthreads();

        int node = base + nl;
        if (node < NN) {
            float acc = bs[j];
            #pragma unroll
            for (int k = 0; k < 64; k += 4) {
                float4 rv = *(const float4*)&rows[nl][k];
                acc = fmaf(rv.x, Ws[(k + 0) * 32 + j], acc);
                acc = fmaf(rv.y, Ws[(k + 1) * 32 + j], acc);
                acc = fmaf(rv.z, Ws[(k + 2) * 32 + j], acc);
                acc = fmaf(rv.w, Ws[(k + 3) * 32 + j], acc);
            }
            out[(size_t)node * 32 + j] = acc;
        }
    }
}

extern "C" void kernel_launch(void* const* d_in, const int* in_sizes, int n_in,
                              void* d_out, int out_size, void* d_ws, size_t ws_size,
                              hipStream_t stream)
{
    const float* x    = (const float*)d_in[0];
    const int*   ei0  = (const int*)d_in[1];
    const int*   ei1  = (const int*)d_in[2];
    const float* Wl   = (const float*)d_in[3];   // [2,2,64,64]
    const float* Wr   = (const float*)d_in[4];   // [2,2,64,64]
    const float* bl   = (const float*)d_in[5];   // [2,2,64]
    const float* linW = (const float*)d_in[6];   // [64,32]
    const float* linb = (const float*)d_in[7];   // [32]
    float* out = (float*)d_out;

    int E0 = in_sizes[1] / 2;
    int E1 = in_sizes[2] / 2;

    // Workspace: [deg | ovf_cnt | ovf | bins | agg(2*NN*64 f) | h1(NN*64 f) |
    //             xb(NN*64 us) | h1b(NN*64 us)]  ~64.5 MB total
    int*  deg     = (int*)d_ws;
    int*  ovf_cnt = deg + 2 * NN;
    int2* ovf     = (int2*)(ovf_cnt + 4);
    int*  bins    = (int*)(ovf + OVF_CAP);
    float* agg    = (float*)(bins + (size_t)2 * NN * CAP);
    float* agg0   = agg;
    float* agg1   = agg + (size_t)NN * 64;
    float* h1     = agg + (size_t)2 * NN * 64;
    unsigned short* xb  = (unsigned short*)(h1 + (size_t)NN * 64);
    unsigned short* h1b = xb + (size_t)NN * 64;

    dim3 blk(256);
    int ggrid = (NN + 127) / 128;   // 391

    (void)hipMemsetAsync(deg, 0, (2 * NN + 4) * sizeof(int), stream);
    bin_fill<<<2048, blk, 0, stream>>>(ei0, E0, ei1, E1, deg, bins, ovf, ovf_cnt);
    to_bf16<<<1024, blk, 0, stream>>>(x, xb, NN * 16);

    // ---- Layer 0 (gather from xb, self from x) ----
    aggregate<<<4096, blk, 0, stream>>>(bins, deg, xb, agg);
    ovf_fix<<<64, blk, 0, stream>>>(ovf, ovf_cnt, deg, x, agg);
    layer_gemm<<<ggrid, blk, 0, stream>>>(agg0, agg1, x,
        Wl + 0, Wl + 4096, Wr + 0, Wr + 4096, bl + 0, bl + 64, h1, h1b);

    // ---- Layer 1 (gather from h1b, self from h1, in-place) ----
    aggregate<<<4096, blk, 0, stream>>>(bins, deg, h1b, agg);
    ovf_fix<<<64, blk, 0, stream>>>(ovf, ovf_cnt, deg, h1, agg);
    layer_gemm<<<ggrid, blk, 0, stream>>>(agg0, agg1, h1,
        Wl + 8192, Wl + 12288, Wr + 8192, Wr + 12288, bl + 128, bl + 192, h1, (unsigned short*)nullptr);

    // ---- Final projection ----
    final_gemm<<<768, blk, 0, stream>>>(h1, linW, linb, out);
}

// Round 7
// 309.664 us; speedup vs baseline: 1.3736x; 1.0572x over previous
//
#include <hip/hip_runtime.h>

#define NN 50000
#define CAP 32          // per-node bin capacity; overflow handled correctly
#define OVF_CAP 4096
#define SHARD_W 12500   // contiguous task range per shard group (2*NN / 8)

__device__ __forceinline__ unsigned short f2bf(float f) {
    unsigned u = __float_as_uint(f);
    u += 0x7fffu + ((u >> 16) & 1u);           // round-to-nearest-even
    return (unsigned short)(u >> 16);
}
__device__ __forceinline__ float bf2f(unsigned short u) {
    return __uint_as_float(((unsigned)u) << 16);
}

// fp32 -> bf16 row copy (n4 = count of float4s)
__global__ __launch_bounds__(256) void to_bf16(
    const float* __restrict__ in, unsigned short* __restrict__ out, int n4)
{
    int stride = gridDim.x * blockDim.x;
    for (int i = blockIdx.x * blockDim.x + threadIdx.x; i < n4; i += stride) {
        float4 v = ((const float4*)in)[i];
        ushort4 o;
        o.x = f2bf(v.x); o.y = f2bf(v.y); o.z = f2bf(v.z); o.w = f2bf(v.w);
        ((ushort4*)out)[i] = o;
    }
}

// Range-sharded bin fill. Group g = blockIdx&7 (round-robin -> XCD g) owns the
// CONTIGUOUS task range [g*12500, (g+1)*12500): its 1.6MB bin region maps
// across all L2 sets (R6's node&7 sharding put shard lines at stride 1024B ->
// only 1/8 of L2 sets -> thrash; plus bins was not 128B-aligned -> every bin
// straddled 2 lines). Ranges don't straddle relations: groups 0-3 scan only
// ei0, groups 4-7 only ei1 (halves rescan reads). No NT loads (R6: -9us).
__global__ __launch_bounds__(256) void bin_fill(
    const int* __restrict__ ei0, int E0,
    const int* __restrict__ ei1, int E1,
    int* __restrict__ deg, int* __restrict__ bins,
    int2* __restrict__ ovf, int* __restrict__ ovf_cnt)
{
    int grp  = blockIdx.x & 7;
    int lblk = blockIdx.x >> 3;
    int lgrid = gridDim.x >> 3;
    const int* ei; int E; int baseT;
    if (grp < 4) { ei = ei0; E = E0; baseT = 0; }
    else         { ei = ei1; E = E1; baseT = NN; }
    int ls = grp & 3;   // local shard within this relation's 4 ranges

    int stride = lgrid * blockDim.x;
    for (int t = lblk * blockDim.x + threadIdx.x; t < E; t += stride) {
        int dstv = ei[E + t];
        int task = baseT + dstv;
        if ((task / SHARD_W) - ((grp < 4) ? 0 : 4) == ls) {
            int s = ei[t];
            int r = atomicAdd(&deg[task], 1);
            if (r < CAP) {
                bins[(size_t)task * CAP + r] = s;
            } else {
                int o = atomicAdd(ovf_cnt, 1);
                if (o < OVF_CAP) ovf[o] = make_int2(task, s);
            }
        }
    }
}

// One (rel,node) task per wave, 4 independent bf16 gather chains (R4/R6 form).
__global__ __launch_bounds__(256) void aggregate(
    const int* __restrict__ bins, const int* __restrict__ deg,
    const unsigned short* __restrict__ hb, float* __restrict__ agg)
{
    int lane = threadIdx.x & 63;
    int wid = (blockIdx.x * blockDim.x + threadIdx.x) >> 6;
    int nwaves = (gridDim.x * blockDim.x) >> 6;
    for (int task = wid; task < 2 * NN; task += nwaves) {
        int d = deg[task];
        int m = min(d, CAP);
        int idx = 0;
        if (lane < m) idx = bins[(size_t)task * CAP + lane];
        float a0 = 0.f, a1 = 0.f, a2 = 0.f, a3 = 0.f;
        int t = 0;
        for (; t + 4 <= m; t += 4) {
            int s0 = __shfl(idx, t + 0);
            int s1 = __shfl(idx, t + 1);
            int s2 = __shfl(idx, t + 2);
            int s3 = __shfl(idx, t + 3);
            a0 += bf2f(hb[(size_t)s0 * 64 + lane]);
            a1 += bf2f(hb[(size_t)s1 * 64 + lane]);
            a2 += bf2f(hb[(size_t)s2 * 64 + lane]);
            a3 += bf2f(hb[(size_t)s3 * 64 + lane]);
        }
        for (; t < m; ++t) {
            int s = __shfl(idx, t);
            a0 += bf2f(hb[(size_t)s * 64 + lane]);
        }
        float sum = (a0 + a1) + (a2 + a3);
        agg[(size_t)task * 64 + lane] = sum / (float)max(d, 1);
    }
}

// Overflow fixup on fp32 h (tiny work).
__global__ __launch_bounds__(256) void ovf_fix(
    const int2* __restrict__ ovf, const int* __restrict__ ovf_cnt,
    const int* __restrict__ deg, const float* __restrict__ h,
    float* __restrict__ agg)
{
    int cnt = min(*ovf_cnt, OVF_CAP);
    int total = cnt * 64;
    int stride = gridDim.x * blockDim.x;
    for (int t = blockIdx.x * blockDim.x + threadIdx.x; t < total; t += stride) {
        int e = t >> 6, f = t & 63;
        int2 v = ovf[e];
        float val = h[(size_t)v.y * 64 + f] / (float)max(deg[v.x], 1);
        atomicAdd(&agg[(size_t)v.x * 64 + f], val);
    }
}

// hout = relu(mean0@Wl0 + mean1@Wl1 + h@(Wr0+Wr1) + (b0+b1))
#define RST 132
__global__ __launch_bounds__(256) void layer_gemm(
    const float* __restrict__ agg0, const float* __restrict__ agg1,
    const float* __restrict__ h,
    const float* __restrict__ Wl0, const float* __restrict__ Wl1,
    const float* __restrict__ Wr0, const float* __restrict__ Wr1,
    const float* __restrict__ b0, const float* __restrict__ b1,
    float* __restrict__ hout, unsigned short* __restrict__ hb16)
{
    __shared__ float Wch[64 * 64];
    __shared__ float rowsT[64 * RST];
    __shared__ float bias[64];

    int tid = threadIdx.x;
    int base = blockIdx.x * 128;
    if (tid < 64) bias[tid] = b0[tid] + b1[tid];

    int j8 = (tid & 7) * 8;
    int n4 = (tid >> 3) * 4;

    float acc[4][8];
    #pragma unroll
    for (int i = 0; i < 4; i++)
        #pragma unroll
        for (int c = 0; c < 8; c++) acc[i][c] = 0.f;

    for (int chunk = 0; chunk < 3; chunk++) {
        const float* W   = (chunk == 0) ? Wl0  : (chunk == 1) ? Wl1  : Wr0;
        const float* src = (chunk == 0) ? agg0 : (chunk == 1) ? agg1 : h;
        __syncthreads();
        #pragma unroll
        for (int r = 0; r < 4; r++) {
            int i = tid + 256 * r;
            float4 w = *(const float4*)&W[i * 4];
            if (chunk == 2) {
                float4 w2 = *(const float4*)&Wr1[i * 4];
                w.x += w2.x; w.y += w2.y; w.z += w2.z; w.w += w2.w;
            }
            *(float4*)&Wch[i * 4] = w;
        }
        #pragma unroll
        for (int r = 0; r < 8; r++) {
            int i = tid + 256 * r;
            int node = i >> 4;
            int k4 = (i & 15) * 4;
            float4 v = make_float4(0.f, 0.f, 0.f, 0.f);
            int g = base + node;
            if (g < NN) v = *(const float4*)&src[(size_t)g * 64 + k4];
            rowsT[(k4 + 0) * RST + node] = v.x;
            rowsT[(k4 + 1) * RST + node] = v.y;
            rowsT[(k4 + 2) * RST + node] = v.z;
            rowsT[(k4 + 3) * RST + node] = v.w;
        }
        __syncthreads();
        #pragma unroll 4
        for (int k = 0; k < 64; k++) {
            float4 wa = *(const float4*)&Wch[k * 64 + j8];
            float4 wb = *(const float4*)&Wch[k * 64 + j8 + 4];
            float4 rv = *(const float4*)&rowsT[k * RST + n4];
            float w[8] = {wa.x, wa.y, wa.z, wa.w, wb.x, wb.y, wb.z, wb.w};
            float rr[4] = {rv.x, rv.y, rv.z, rv.w};
            #pragma unroll
            for (int i = 0; i < 4; i++)
                #pragma unroll
                for (int c = 0; c < 8; c++)
                    acc[i][c] = fmaf(rr[i], w[c], acc[i][c]);
        }
    }

    #pragma unroll
    for (int i = 0; i < 4; i++) {
        int g = base + n4 + i;
        if (g < NN) {
            float4 o1, o2;
            o1.x = fmaxf(acc[i][0] + bias[j8 + 0], 0.f);
            o1.y = fmaxf(acc[i][1] + bias[j8 + 1], 0.f);
            o1.z = fmaxf(acc[i][2] + bias[j8 + 2], 0.f);
            o1.w = fmaxf(acc[i][3] + bias[j8 + 3], 0.f);
            o2.x = fmaxf(acc[i][4] + bias[j8 + 4], 0.f);
            o2.y = fmaxf(acc[i][5] + bias[j8 + 5], 0.f);
            o2.z = fmaxf(acc[i][6] + bias[j8 + 6], 0.f);
            o2.w = fmaxf(acc[i][7] + bias[j8 + 7], 0.f);
            *(float4*)&hout[(size_t)g * 64 + j8]     = o1;
            *(float4*)&hout[(size_t)g * 64 + j8 + 4] = o2;
            if (hb16) {
                ushort4 p0, p1;
                p0.x = f2bf(o1.x); p0.y = f2bf(o1.y); p0.z = f2bf(o1.z); p0.w = f2bf(o1.w);
                p1.x = f2bf(o2.x); p1.y = f2bf(o2.y); p1.z = f2bf(o2.z); p1.w = f2bf(o2.w);
                *(ushort4*)&hb16[(size_t)g * 64 + j8]     = p0;
                *(ushort4*)&hb16[(size_t)g * 64 + j8 + 4] = p1;
            }
        }
    }
}

// out[i,:32] = h[i,:64] @ W + b
__global__ __launch_bounds__(256) void final_gemm(
    const float* __restrict__ h, const float* __restrict__ W,
    const float* __restrict__ b, float* __restrict__ out)
{
    __shared__ float Ws[64 * 32];
    __shared__ float bs[32];
    __shared__ float rows[8][64];

    int tid = threadIdx.x;
    for (int i = tid; i < 2048; i += 256) Ws[i] = W[i];
    if (tid < 32) bs[tid] = b[tid];

    int j = tid & 31;
    int nl = tid >> 5;

    for (int base = blockIdx.x * 8; base < NN; base += gridDim.x * 8) {
        __syncthreads();
        if (tid < 128) {
            int n = tid >> 4, kq = tid & 15;
            int node = base + n;
            float4 v = make_float4(0.f, 0.f, 0.f, 0.f);
            if (node < NN) v = *(const float4*)&h[(size_t)node * 64 + kq * 4];
            *(float4*)&rows[n][kq * 4] = v;
        }
        __syncthreads();

        int node = base + nl;
        if (node < NN) {
            float acc = bs[j];
            #pragma unroll
            for (int k = 0; k < 64; k += 4) {
                float4 rv = *(const float4*)&rows[nl][k];
                acc = fmaf(rv.x, Ws[(k + 0) * 32 + j], acc);
                acc = fmaf(rv.y, Ws[(k + 1) * 32 + j], acc);
                acc = fmaf(rv.z, Ws[(k + 2) * 32 + j], acc);
                acc = fmaf(rv.w, Ws[(k + 3) * 32 + j], acc);
            }
            out[(size_t)node * 32 + j] = acc;
        }
    }
}

extern "C" void kernel_launch(void* const* d_in, const int* in_sizes, int n_in,
                              void* d_out, int out_size, void* d_ws, size_t ws_size,
                              hipStream_t stream)
{
    const float* x    = (const float*)d_in[0];
    const int*   ei0  = (const int*)d_in[1];
    const int*   ei1  = (const int*)d_in[2];
    const float* Wl   = (const float*)d_in[3];   // [2,2,64,64]
    const float* Wr   = (const float*)d_in[4];   // [2,2,64,64]
    const float* bl   = (const float*)d_in[5];   // [2,2,64]
    const float* linW = (const float*)d_in[6];   // [64,32]
    const float* linb = (const float*)d_in[7];   // [32]
    float* out = (float*)d_out;

    int E0 = in_sizes[1] / 2;
    int E1 = in_sizes[2] / 2;

    // Workspace, 128B-aligned-large-buffers-first (bins MUST be line-aligned;
    // R6 had it at +432784B -> every 128B bin straddled two cache lines):
    // [bins 12.8MB | agg 25.6MB | h1 12.8MB | xb 6.4MB | h1b 6.4MB |
    //  deg 400KB | ovf_cnt | ovf]  ~64.5 MB
    int*   bins = (int*)d_ws;
    float* agg  = (float*)(bins + (size_t)2 * NN * CAP);
    float* agg0 = agg;
    float* agg1 = agg + (size_t)NN * 64;
    float* h1   = agg + (size_t)2 * NN * 64;
    unsigned short* xb  = (unsigned short*)(h1 + (size_t)NN * 64);
    unsigned short* h1b = xb + (size_t)NN * 64;
    int*  deg     = (int*)(h1b + (size_t)NN * 64);
    int*  ovf_cnt = deg + 2 * NN;
    int2* ovf     = (int2*)(ovf_cnt + 4);

    dim3 blk(256);
    int ggrid = (NN + 127) / 128;   // 391

    (void)hipMemsetAsync(deg, 0, (2 * NN + 4) * sizeof(int), stream);
    bin_fill<<<2048, blk, 0, stream>>>(ei0, E0, ei1, E1, deg, bins, ovf, ovf_cnt);
    to_bf16<<<1024, blk, 0, stream>>>(x, xb, NN * 16);

    // ---- Layer 0 (gather from xb, self from x) ----
    aggregate<<<4096, blk, 0, stream>>>(bins, deg, xb, agg);
    ovf_fix<<<64, blk, 0, stream>>>(ovf, ovf_cnt, deg, x, agg);
    layer_gemm<<<ggrid, blk, 0, stream>>>(agg0, agg1, x,
        Wl + 0, Wl + 4096, Wr + 0, Wr + 4096, bl + 0, bl + 64, h1, h1b);

    // ---- Layer 1 (gather from h1b, self from h1, in-place) ----
    aggregate<<<4096, blk, 0, stream>>>(bins, deg, h1b, agg);
    ovf_fix<<<64, blk, 0, stream>>>(ovf, ovf_cnt, deg, h1, agg);
    layer_gemm<<<ggrid, blk, 0, stream>>>(agg0, agg1, h1,
        Wl + 8192, Wl + 12288, Wr + 8192, Wr + 12288, bl + 128, bl + 192, h1, (unsigned short*)nullptr);

    // ---- Final projection ----
    final_gemm<<<768, blk, 0, stream>>>(h1, linW, linb, out);
}